// Round 10
// baseline (354.533 us; speedup 1.0000x reference)
//
#include <hip/hip_runtime.h>

// PhysicsConstrainedLoss: 6 loss terms over 6.4M edges / 200K nodes.
// R9: revert to R7 grid (6250 x 256, best measured). De-serialize p1:
// all-wave redundant prefix scan (same-value LDS writes are benign) + cursor
// pre-init at kernel start -> barrier B2 and the wave0-only scan phase are
// gone (6 -> 4 syncs/block). node_pass vectorized int4. PLUS a sacrificial
// diagnostic: p1_probe (post-finalize, scratch output, asm-sunk per DCE rule)
// runs the pure load+gather+compute body 3x over shifted tiles; its top-5
// rocprof duration / 3 = p1's irreducible floor. Dropped next round.

constexpr int   kNodes         = 200000;
constexpr int   kEdges         = 6400000;
constexpr int   kNumSums       = 9;
constexpr float kEps           = 1e-6f;

constexpr int   kBucketShift   = 12;                 // 4096 nodes / bucket
constexpr int   kBucketSize    = 1 << kBucketShift;
constexpr int   kBuckets       = (kNodes + kBucketSize - 1) / kBucketSize;  // 49
constexpr int   kEdgesPerBlk   = 1024;
constexpr int   kEdgesPerThr   = 4;
constexpr int   kP1Blocks      = kEdges / kEdgesPerBlk;   // 6250
static_assert(kEdges % kEdgesPerBlk == 0, "exact tiling assumed");
constexpr int   kEntriesPerBlk = 2 * kEdgesPerBlk;   // 2048
constexpr int   kOffStride     = 52;                 // uint16 stride per tile
constexpr int   kSlabs         = 16;
constexpr int   kTilesPerSlab  = (kP1Blocks + kSlabs - 1) / kSlabs;  // 391
constexpr int   kP2Blocks      = kBuckets * kSlabs;  // 784
constexpr int   kNodeBlocks    = 200;
constexpr int   kFbBlocks      = 2048;
constexpr float kQScale        = 65536.0f;
constexpr float kQInv          = 1.0f / 65536.0f;
constexpr int   kQBias         = 524288;             // int20 bias

__device__ __forceinline__ float softplusf(float t) {
    return fmaxf(t, 0.0f) + log1pf(expf(-fabsf(t)));
}

// ---------------------------------------------------------------- pre-pass
__global__ __launch_bounds__(256) void compact_nf(
    const float4* __restrict__ nf4,   // (N,4)
    float2*       __restrict__ nfc)   // (N,) packed {vr, vi}
{
    const int i = blockIdx.x * 256 + threadIdx.x;
    if (i < kNodes) {
        const float4 v = nf4[i];
        nfc[i] = make_float2(v.x, v.y);
    }
}

// ---------------------------------------------------------------- phase 1
__global__ __launch_bounds__(256) void p1_edges(
    const float2* __restrict__ nfc,     // compact (N,) {vr,vi}
    const float*  __restrict__ logits,
    const float*  __restrict__ eparams,
    const float*  __restrict__ labels,
    const float*  __restrict__ tparams,
    const int*    __restrict__ srcs,
    const int*    __restrict__ dsts,
    unsigned*       __restrict__ pairs,    // (kP1Blocks, kEntriesPerBlk)
    unsigned short* __restrict__ offs_g,   // (kP1Blocks, kOffStride)
    float*          __restrict__ partials) // (kP1Blocks, kNumSums)
{
    __shared__ __align__(16) unsigned sorted[kEntriesPerBlk];  // 8 KB
    __shared__ int   hist[kBuckets];
    __shared__ int   offs[kBuckets + 1];
    __shared__ int   cursor[kBuckets];
    __shared__ float smem[4][kNumSums];

    const int tid = threadIdx.x;
    if (tid < kBuckets) { hist[tid] = 0; cursor[tid] = 0; }
    __syncthreads();                       // S0: init visible

    float acc[kNumSums];
#pragma unroll
    for (int k = 0; k < kNumSums; ++k) acc[k] = 0.0f;

    unsigned ent[2 * kEdgesPerThr];  // 8 packed entries (static idx, unrolled)

    const int e0 = blockIdx.x * kEdgesPerBlk;
    const int q4 = (e0 >> 2) + tid;   // index into float4/int4 views

    // ---- all index loads first
    const int4 ss = reinterpret_cast<const int4*>(srcs)[q4];
    const int4 dd = reinterpret_cast<const int4*>(dsts)[q4];

    // ---- all 8 gathers issued back-to-back (independent)
    const float2 vs0 = nfc[ss.x];
    const float2 vs1 = nfc[ss.y];
    const float2 vs2 = nfc[ss.z];
    const float2 vs3 = nfc[ss.w];
    const float2 vd0 = nfc[dd.x];
    const float2 vd1 = nfc[dd.y];
    const float2 vd2 = nfc[dd.z];
    const float2 vd3 = nfc[dd.w];

    // ---- stream loads
    const float4 lx = reinterpret_cast<const float4*>(logits)[q4];
    const float4 ly = reinterpret_cast<const float4*>(labels)[q4];
    const float4 ea = reinterpret_cast<const float4*>(eparams)[2 * q4];
    const float4 eb = reinterpret_cast<const float4*>(eparams)[2 * q4 + 1];
    const float4 ta = reinterpret_cast<const float4*>(tparams)[2 * q4];
    const float4 tb = reinterpret_cast<const float4*>(tparams)[2 * q4 + 1];

    const float xs[4]  = {lx.x, lx.y, lx.z, lx.w};
    const float ys[4]  = {ly.x, ly.y, ly.z, ly.w};
    const float epr[4] = {ea.x, ea.z, eb.x, eb.z};
    const float epx[4] = {ea.y, ea.w, eb.y, eb.w};
    const float tpr[4] = {ta.x, ta.z, tb.x, tb.z};
    const float tpx[4] = {ta.y, ta.w, tb.y, tb.w};
    const float2 vss[4] = {vs0, vs1, vs2, vs3};
    const float2 vdd[4] = {vd0, vd1, vd2, vd3};
    const int    sn[4]  = {ss.x, ss.y, ss.z, ss.w};
    const int    dn[4]  = {dd.x, dd.y, dd.z, dd.w};

    unsigned bp0 = 0, bp1 = 0;
#pragma unroll
    for (int j = 0; j < kEdgesPerThr; ++j) {
        const float x = xs[j], y = ys[j];
        const float er = epr[j], ex = epx[j];

        const float t      = __expf(-fabsf(x));
        const float inv1pt = __builtin_amdgcn_rcpf(1.0f + t);
        const float p      = (x >= 0.0f) ? inv1pt : t * inv1pt;
        const float sp_nx  = fmaxf(-x, 0.0f) + __logf(1.0f + t); // softplus(-x)
        const float bce    = sp_nx + (1.0f - y) * x;

        const float dr  = er - tpr[j];
        const float dxx = ex - tpx[j];

        const float dvr = vss[j].x - vdd[j].x;
        const float dvi = vss[j].y - vdd[j].y;
        const float mag = sqrtf(dvr * dvr + dvi * dvi);

        const float Rp    = er + kEps;
        const float curp  = mag * rsqrtf(Rp * Rp + ex * ex) * p;
        const float vdrop = mag * p;

        acc[0] += bce;
        acc[1] += dr * dr + dxx * dxx;
        acc[2] += p;
        acc[3] += p * er;
        acc[4] += p * ex;
        acc[5] += p * er * er;
        acc[6] += p * ex * ex;
        acc[7] += vdrop;
        acc[8] += vdrop * vdrop;

        int q = __float2int_rn(curp * kQScale);
        q = max(-(kQBias - 1), min(kQBias - 1, q));

        const int bd = dn[j] >> kBucketShift;
        const int bs = sn[j] >> kBucketShift;
        atomicAdd(&hist[bd], 1);
        atomicAdd(&hist[bs], 1);

        ent[2 * j]     = ((unsigned)(dn[j] & (kBucketSize - 1)) << 20) | (unsigned)( q + kQBias);
        ent[2 * j + 1] = ((unsigned)(sn[j] & (kBucketSize - 1)) << 20) | (unsigned)(-q + kQBias);
        if (j < 2) {
            bp0 |= ((unsigned)bd) << (16 * j);
            bp0 |= ((unsigned)bs) << (16 * j + 8);
        } else {
            bp1 |= ((unsigned)bd) << (16 * (j - 2));
            bp1 |= ((unsigned)bs) << (16 * (j - 2) + 8);
        }
    }

    __syncthreads();                       // S1: histogram complete

    // ---- ALL-WAVE redundant exclusive scan (same-value writes are benign;
    //      no B2: cursor was pre-initialized at S0, hist is only read here)
    {
        const int lane = tid & 63;
        int h    = (lane < kBuckets) ? hist[lane] : 0;
        int incl = h;
#pragma unroll
        for (int o = 1; o < 64; o <<= 1) {
            int n = __shfl_up(incl, o, 64);
            if (lane >= o) incl += n;
        }
        if (lane < kBuckets + 1) offs[lane] = incl - h;  // lane 49: incl=2048,h=0
    }
    // within-wave LDS write->read ordering is handled by lgkmcnt; every wave
    // wrote the complete offs[] itself, so no cross-wave barrier is needed.

    // ---- scatter registers -> bucket-sorted LDS
    {
        const unsigned bkp[2] = {bp0, bp1};
#pragma unroll
        for (int k = 0; k < 2 * kEdgesPerThr; ++k) {
            const int b   = (int)((bkp[k >> 2] >> ((k & 3) * 8)) & 0xFFu);
            const int pos = offs[b] + atomicAdd(&cursor[b], 1);
            sorted[pos] = ent[k];
        }
    }
    __syncthreads();                       // S2: sorted complete

    // ---- fully-coalesced copy-out to the block's fixed slot range
    {
        const uint4 v0 = *reinterpret_cast<const uint4*>(&sorted[tid * 4]);
        reinterpret_cast<uint4*>(pairs + (size_t)blockIdx.x * kEntriesPerBlk)[tid] = v0;
        const uint4 v1 = *reinterpret_cast<const uint4*>(&sorted[1024 + tid * 4]);
        reinterpret_cast<uint4*>(pairs + (size_t)blockIdx.x * kEntriesPerBlk)[256 + tid] = v1;
    }
    if (tid < kBuckets + 1)
        offs_g[(size_t)blockIdx.x * kOffStride + tid] = (unsigned short)offs[tid];

    // ---- block reduction of the 9 scalar sums (no barrier needed before:
    //      shfl is wave-local and smem is disjoint from sort arrays)
    const int lane = tid & 63;
    const int wave = tid >> 6;
#pragma unroll
    for (int k = 0; k < kNumSums; ++k) {
        float v = acc[k];
#pragma unroll
        for (int off = 32; off > 0; off >>= 1) v += __shfl_down(v, off, 64);
        if (lane == 0) smem[wave][k] = v;
    }
    __syncthreads();                       // S3: smem visible
    if (tid < kNumSums) {
        float v = 0.0f;
#pragma unroll
        for (int w = 0; w < 4; ++w) v += smem[w][tid];
        partials[blockIdx.x * kNumSums + tid] = v;
    }
}

// ---------------------------------------------------------------- phase 2
__global__ __launch_bounds__(256) void p2_buckets(
    const unsigned*       __restrict__ pairs,
    const unsigned short* __restrict__ offs_g,
    int*                  __restrict__ out_i32)  // (kP2Blocks, kBucketSize)
{
    __shared__ int accs[kBucketSize];
    const int b    = blockIdx.x / kSlabs;
    const int slab = blockIdx.x % kSlabs;

    for (int i = threadIdx.x; i < kBucketSize; i += 256) accs[i] = 0;
    __syncthreads();

    const int i0 = slab * kTilesPerSlab;
    const int i1 = min(i0 + kTilesPerSlab, kP1Blocks);
    const int lane = threadIdx.x & 63;
    const int wave = threadIdx.x >> 6;

    // each wave walks one tile's run for this bucket
    for (int i = i0 + wave; i < i1; i += 4) {
        const int o0 = (int)offs_g[(size_t)i * kOffStride + b];
        const int o1 = (int)offs_g[(size_t)i * kOffStride + b + 1];
        const unsigned* pb = pairs + (size_t)i * kEntriesPerBlk;
        for (int j = o0 + lane; j < o1; j += 64) {
            const unsigned u = pb[j];
            atomicAdd(&accs[u >> 20], (int)(u & 0xFFFFFu) - kQBias);
        }
    }
    __syncthreads();

    int* o = out_i32 + (size_t)blockIdx.x * kBucketSize;
    for (int i = threadIdx.x; i < kBucketSize; i += 256) o[i] = accs[i];
}

// ---------------------------------------------------------------- node pass
__global__ __launch_bounds__(256) void node_pass_binned(
    const int* __restrict__ out_i32,
    float*     __restrict__ node_partials)
{
    float acc = 0.0f;
    const int stride = gridDim.x * blockDim.x;
    // 4 consecutive nodes per thread via int4 (200000 % 4 == 0)
    for (int n4 = blockIdx.x * blockDim.x + threadIdx.x; n4 < kNodes / 4; n4 += stride) {
        const int n = n4 * 4;
        const int b = n >> kBucketShift;
        const int s = n & (kBucketSize - 1);
        const int* p = out_i32 + ((size_t)b * kSlabs) * kBucketSize + s;
        int4 v = make_int4(0, 0, 0, 0);
#pragma unroll
        for (int m = 0; m < kSlabs; ++m) {
            const int4 w = *reinterpret_cast<const int4*>(p + (size_t)m * kBucketSize);
            v.x += w.x; v.y += w.y; v.z += w.z; v.w += w.w;
        }
        const float f0 = (float)v.x * kQInv;
        const float f1 = (float)v.y * kQInv;
        const float f2 = (float)v.z * kQInv;
        const float f3 = (float)v.w * kQInv;
        acc += f0 * f0 + f1 * f1 + f2 * f2 + f3 * f3;
    }
    __shared__ float smem[4];
    const int lane = threadIdx.x & 63;
    const int wave = threadIdx.x >> 6;
    float v = acc;
#pragma unroll
    for (int off = 32; off > 0; off >>= 1) v += __shfl_down(v, off, 64);
    if (lane == 0) smem[wave] = v;
    __syncthreads();
    if (threadIdx.x == 0)
        node_partials[blockIdx.x] = smem[0] + smem[1] + smem[2] + smem[3];
}

// ---------------------------------------------------------------- DIAGNOSTIC
// Pure load+gather+compute floor probe: 3 passes over shifted tile windows,
// no LDS/sort/copyout. Entries kept live via asm sink (DCE rule #17).
// Runs AFTER finalize; writes to already-consumed scratch. Dropped in R10.
__global__ __launch_bounds__(256) void p1_probe(
    const float2* __restrict__ nfc,
    const float*  __restrict__ logits,
    const float*  __restrict__ eparams,
    const float*  __restrict__ labels,
    const float*  __restrict__ tparams,
    const int*    __restrict__ srcs,
    const int*    __restrict__ dsts,
    float*        __restrict__ scratch)   // reuses partials region
{
    const int tid = threadIdx.x;
    float acc[kNumSums];
#pragma unroll
    for (int k = 0; k < kNumSums; ++k) acc[k] = 0.0f;

#pragma unroll 1
    for (int r = 0; r < 3; ++r) {
        const int gb = (blockIdx.x + r * 2083) % kP1Blocks;
        const int q4 = gb * 256 + tid;

        const int4 ss = reinterpret_cast<const int4*>(srcs)[q4];
        const int4 dd = reinterpret_cast<const int4*>(dsts)[q4];

        const float2 vs0 = nfc[ss.x];
        const float2 vs1 = nfc[ss.y];
        const float2 vs2 = nfc[ss.z];
        const float2 vs3 = nfc[ss.w];
        const float2 vd0 = nfc[dd.x];
        const float2 vd1 = nfc[dd.y];
        const float2 vd2 = nfc[dd.z];
        const float2 vd3 = nfc[dd.w];

        const float4 lx = reinterpret_cast<const float4*>(logits)[q4];
        const float4 ly = reinterpret_cast<const float4*>(labels)[q4];
        const float4 ea = reinterpret_cast<const float4*>(eparams)[2 * q4];
        const float4 eb = reinterpret_cast<const float4*>(eparams)[2 * q4 + 1];
        const float4 ta = reinterpret_cast<const float4*>(tparams)[2 * q4];
        const float4 tb = reinterpret_cast<const float4*>(tparams)[2 * q4 + 1];

        const float xs[4]  = {lx.x, lx.y, lx.z, lx.w};
        const float ys[4]  = {ly.x, ly.y, ly.z, ly.w};
        const float epr[4] = {ea.x, ea.z, eb.x, eb.z};
        const float epx[4] = {ea.y, ea.w, eb.y, eb.w};
        const float tpr[4] = {ta.x, ta.z, tb.x, tb.z};
        const float tpx[4] = {ta.y, ta.w, tb.y, tb.w};
        const float2 vss[4] = {vs0, vs1, vs2, vs3};
        const float2 vdd[4] = {vd0, vd1, vd2, vd3};
        const int    sn[4]  = {ss.x, ss.y, ss.z, ss.w};
        const int    dn[4]  = {dd.x, dd.y, dd.z, dd.w};

#pragma unroll
        for (int j = 0; j < kEdgesPerThr; ++j) {
            const float x = xs[j], y = ys[j];
            const float er = epr[j], ex = epx[j];

            const float t      = __expf(-fabsf(x));
            const float inv1pt = __builtin_amdgcn_rcpf(1.0f + t);
            const float p      = (x >= 0.0f) ? inv1pt : t * inv1pt;
            const float sp_nx  = fmaxf(-x, 0.0f) + __logf(1.0f + t);
            const float bce    = sp_nx + (1.0f - y) * x;

            const float dr  = er - tpr[j];
            const float dxx = ex - tpx[j];
            const float dvr = vss[j].x - vdd[j].x;
            const float dvi = vss[j].y - vdd[j].y;
            const float mag = sqrtf(dvr * dvr + dvi * dvi);
            const float Rp    = er + kEps;
            const float curp  = mag * rsqrtf(Rp * Rp + ex * ex) * p;
            const float vdrop = mag * p;

            acc[0] += bce;
            acc[1] += dr * dr + dxx * dxx;
            acc[2] += p;
            acc[3] += p * er;
            acc[4] += p * ex;
            acc[5] += p * er * er;
            acc[6] += p * ex * ex;
            acc[7] += vdrop;
            acc[8] += vdrop * vdrop;

            int q = __float2int_rn(curp * kQScale);
            q = max(-(kQBias - 1), min(kQBias - 1, q));
            unsigned e0 = ((unsigned)(dn[j] & (kBucketSize - 1)) << 20) | (unsigned)( q + kQBias);
            unsigned e1 = ((unsigned)(sn[j] & (kBucketSize - 1)) << 20) | (unsigned)(-q + kQBias);
            unsigned bb = ((unsigned)(dn[j] >> kBucketShift) << 8) | (unsigned)(sn[j] >> kBucketShift);
            asm volatile("" :: "v"(e0), "v"(e1), "v"(bb));   // keep live, no DCE
        }
    }

    __shared__ float smem[4][kNumSums];
    const int lane = tid & 63;
    const int wave = tid >> 6;
#pragma unroll
    for (int k = 0; k < kNumSums; ++k) {
        float v = acc[k];
#pragma unroll
        for (int off = 32; off > 0; off >>= 1) v += __shfl_down(v, off, 64);
        if (lane == 0) smem[wave][k] = v;
    }
    __syncthreads();
    if (tid < kNumSums) {
        float v = 0.0f;
#pragma unroll
        for (int w = 0; w < 4; ++w) v += smem[w][tid];
        scratch[blockIdx.x * kNumSums + tid] = v;
    }
}

// ---------------------------------------------------------------- fallback (atomic path)
__global__ __launch_bounds__(256) void edge_pass_atomic(
    const float* __restrict__ nf, const float* __restrict__ logits,
    const float* __restrict__ eparams, const float* __restrict__ labels,
    const float* __restrict__ tparams, const int* __restrict__ srcs,
    const int* __restrict__ dsts, float* __restrict__ node_cur,
    float* __restrict__ partials)
{
    float acc[kNumSums];
#pragma unroll
    for (int k = 0; k < kNumSums; ++k) acc[k] = 0.0f;
    const int stride = gridDim.x * blockDim.x;
    for (int e = blockIdx.x * blockDim.x + threadIdx.x; e < kEdges; e += stride) {
        float  x  = logits[e];
        float  y  = labels[e];
        float2 ep = *reinterpret_cast<const float2*>(eparams + 2 * e);
        float2 tp = *reinterpret_cast<const float2*>(tparams + 2 * e);
        int    s  = srcs[e];
        int    d  = dsts[e];
        float2 vs = *reinterpret_cast<const float2*>(nf + 4 * s);
        float2 vd = *reinterpret_cast<const float2*>(nf + 4 * d);
        float p   = 1.0f / (1.0f + expf(-x));
        float bce = y * softplusf(-x) + (1.0f - y) * softplusf(x);
        float dr = ep.x - tp.x, dxx = ep.y - tp.y;
        float dvr = vs.x - vd.x, dvi = vs.y - vd.y;
        float mag = sqrtf(dvr * dvr + dvi * dvi);
        float Rp  = ep.x + kEps;
        float den = sqrtf(Rp * Rp + ep.y * ep.y);
        float curp = (mag / den) * p;
        float vdrop = mag * p;
        acc[0] += bce; acc[1] += dr * dr + dxx * dxx; acc[2] += p;
        acc[3] += p * ep.x; acc[4] += p * ep.y;
        acc[5] += p * ep.x * ep.x; acc[6] += p * ep.y * ep.y;
        acc[7] += vdrop; acc[8] += vdrop * vdrop;
        atomicAdd(node_cur + d,  curp);
        atomicAdd(node_cur + s, -curp);
    }
    __shared__ float smem[4][kNumSums];
    const int lane = threadIdx.x & 63, wave = threadIdx.x >> 6;
#pragma unroll
    for (int k = 0; k < kNumSums; ++k) {
        float v = acc[k];
#pragma unroll
        for (int off = 32; off > 0; off >>= 1) v += __shfl_down(v, off, 64);
        if (lane == 0) smem[wave][k] = v;
    }
    __syncthreads();
    if (threadIdx.x < kNumSums) {
        float v = 0.0f;
#pragma unroll
        for (int w = 0; w < 4; ++w) v += smem[w][threadIdx.x];
        partials[blockIdx.x * kNumSums + threadIdx.x] = v;
    }
}

__global__ __launch_bounds__(256) void node_pass_flat(
    const float* __restrict__ node_cur, float* __restrict__ node_partials)
{
    float acc = 0.0f;
    const int stride = gridDim.x * blockDim.x;
    for (int i = blockIdx.x * blockDim.x + threadIdx.x; i < kNodes; i += stride) {
        float v = node_cur[i];
        acc += v * v;
    }
    __shared__ float smem[4];
    const int lane = threadIdx.x & 63, wave = threadIdx.x >> 6;
    float v = acc;
#pragma unroll
    for (int off = 32; off > 0; off >>= 1) v += __shfl_down(v, off, 64);
    if (lane == 0) smem[wave] = v;
    __syncthreads();
    if (threadIdx.x == 0)
        node_partials[blockIdx.x] = smem[0] + smem[1] + smem[2] + smem[3];
}

// ---------------------------------------------------------------- finalize
__global__ __launch_bounds__(256) void finalize(
    const float* __restrict__ partials, int nblocks,
    const float* __restrict__ node_partials, int nnp,
    float*       __restrict__ out)
{
    const int tid  = threadIdx.x;
    const int lane = tid & 63;
    const int wave = tid >> 6;
    __shared__ double red[4][kNumSums + 1];

    double s[kNumSums];
#pragma unroll
    for (int k = 0; k < kNumSums; ++k) s[k] = 0.0;
    for (int i = tid; i < nblocks; i += 256) {
#pragma unroll
        for (int k = 0; k < kNumSums; ++k)
            s[k] += (double)partials[i * kNumSums + k];
    }
    double ns = 0.0;
    for (int i = tid; i < nnp; i += 256) ns += (double)node_partials[i];

#pragma unroll
    for (int k = 0; k < kNumSums + 1; ++k) {
        double v = (k < kNumSums) ? s[k] : ns;
#pragma unroll
        for (int off = 32; off > 0; off >>= 1) v += __shfl_down(v, off, 64);
        if (lane == 0) red[wave][k] = v;
    }
    __syncthreads();

    if (tid == 0) {
        double sums[kNumSums + 1];
#pragma unroll
        for (int k = 0; k < kNumSums + 1; ++k)
            sums[k] = red[0][k] + red[1][k] + red[2][k] + red[3][k];

        const double E = (double)kEdges, N = (double)kNodes;
        const double s_bce = sums[0], s_par = sums[1], s_p = sums[2];
        const double s_pR = sums[3], s_pX = sums[4];
        const double s_pR2 = sums[5], s_pX2 = sums[6];
        const double s_v = sums[7], s_v2 = sums[8];
        const double nsum = sums[9];

        double topology  = s_bce / E;
        double parameter = s_par / (2.0 * E);
        double kcl       = 0.1 * (nsum / N);

        double denom = s_p + (double)kEps;
        double mR = s_pR / denom, mX = s_pX / denom;
        double varR = s_pR2 - 2.0 * mR * s_pR + mR * mR * s_p;
        double varX = s_pX2 - 2.0 * mX * s_pX + mX * mX * s_p;
        double param_consistency = 0.5 * (varR + varX);
        double voltage_consistency = (s_v2 - (s_v * s_v) / E) / (E - 1.0);
        double kvl = 0.1 * (param_consistency + voltage_consistency);

        double ecl = s_p - (N - 1.0);
        ecl = ecl * ecl;
        double radial   = 0.1 * (ecl + 0.1 * (s_p / E));
        double sparsity = 0.01 * (s_p / E);
        double total = topology + parameter + kcl + kvl + radial + sparsity;

        out[0] = (float)topology;  out[1] = (float)parameter;
        out[2] = (float)kcl;       out[3] = (float)kvl;
        out[4] = (float)radial;    out[5] = (float)sparsity;
        out[6] = (float)total;
    }
}

extern "C" void kernel_launch(void* const* d_in, const int* in_sizes, int n_in,
                              void* d_out, int out_size, void* d_ws, size_t ws_size,
                              hipStream_t stream) {
    const float* nf      = (const float*)d_in[0];
    const float* logits  = (const float*)d_in[1];
    const float* eparams = (const float*)d_in[2];
    const float* labels  = (const float*)d_in[3];
    const float* tparams = (const float*)d_in[4];
    const int*   eidx    = (const int*)d_in[5];
    float* out           = (float*)d_out;

    // layout (words): [pairs][out_i32][nfc][offs(u16)][partials][node_partials]
    const size_t n_pairs  = (size_t)kP1Blocks * kEntriesPerBlk;          // 12.8M
    const size_t n_outi32 = (size_t)kP2Blocks * kBucketSize;             // 3.21M
    const size_t n_nfc    = (size_t)kNodes * 2;                          // 400K
    const size_t n_offs_w = ((size_t)kP1Blocks * kOffStride + 1) / 2 + 64;
    const size_t n_words  = n_pairs + n_outi32 + n_nfc + n_offs_w +
                            (size_t)kP1Blocks * kNumSums + kNodeBlocks;

    if (ws_size >= n_words * sizeof(unsigned)) {
        unsigned*       pairs         = (unsigned*)d_ws;
        int*            out_i32       = (int*)(pairs + n_pairs);
        float2*         nfc           = (float2*)(out_i32 + n_outi32);
        unsigned short* offs_g        = (unsigned short*)((unsigned*)nfc + n_nfc);
        float*          partials      = (float*)((unsigned*)offs_g + n_offs_w);
        float*          node_partials = partials + (size_t)kP1Blocks * kNumSums;

        compact_nf<<<(kNodes + 255) / 256, 256, 0, stream>>>(
            (const float4*)nf, nfc);
        p1_edges<<<kP1Blocks, 256, 0, stream>>>(nfc, logits, eparams, labels,
                                                tparams, eidx, eidx + kEdges,
                                                pairs, offs_g, partials);
        p2_buckets<<<kP2Blocks, 256, 0, stream>>>(pairs, offs_g, out_i32);
        node_pass_binned<<<kNodeBlocks, 256, 0, stream>>>(out_i32, node_partials);
        finalize<<<1, 256, 0, stream>>>(partials, kP1Blocks, node_partials,
                                        kNodeBlocks, out);
        // Diagnostic probe (after finalize; writes only to consumed scratch).
        p1_probe<<<kP1Blocks, 256, 0, stream>>>(nfc, logits, eparams, labels,
                                                tparams, eidx, eidx + kEdges,
                                                partials);
    } else {
        float* node_cur      = (float*)d_ws;
        float* partials      = node_cur + kNodes;
        float* node_partials = partials + (size_t)kFbBlocks * kNumSums;

        hipMemsetAsync(node_cur, 0, kNodes * sizeof(float), stream);
        edge_pass_atomic<<<kFbBlocks, 256, 0, stream>>>(nf, logits, eparams, labels,
                                                        tparams, eidx, eidx + kEdges,
                                                        node_cur, partials);
        node_pass_flat<<<kNodeBlocks, 256, 0, stream>>>(node_cur, node_partials);
        finalize<<<1, 256, 0, stream>>>(partials, kFbBlocks, node_partials,
                                        kNodeBlocks, out);
    }
}

// Round 11
// 136.024 us; speedup vs baseline: 2.6064x; 2.6064x over previous
//
#include <hip/hip_runtime.h>

// PhysicsConstrainedLoss: 6 loss terms over 6.4M edges / 200K nodes.
// R10: probe dropped (R9 diagnostic: p1 floor = 69us pure load+gather+compute;
// p1 real ~85us -> near-floor, left unchanged). p2 de-latencied: 512-thread
// blocks (8 waves -> 24 waves/CU, serial run-chain halved) + software
// prefetch of next run's offsets/entries while accumulating current run
// (T14 issue-early pattern; p2 is latency-bound at 12 waves/CU).

constexpr int   kNodes         = 200000;
constexpr int   kEdges         = 6400000;
constexpr int   kNumSums       = 9;
constexpr float kEps           = 1e-6f;

constexpr int   kBucketShift   = 12;                 // 4096 nodes / bucket
constexpr int   kBucketSize    = 1 << kBucketShift;
constexpr int   kBuckets       = (kNodes + kBucketSize - 1) / kBucketSize;  // 49
constexpr int   kEdgesPerBlk   = 1024;
constexpr int   kEdgesPerThr   = 4;
constexpr int   kP1Blocks      = kEdges / kEdgesPerBlk;   // 6250
static_assert(kEdges % kEdgesPerBlk == 0, "exact tiling assumed");
constexpr int   kEntriesPerBlk = 2 * kEdgesPerBlk;   // 2048
constexpr int   kOffStride     = 52;                 // uint16 stride per tile
constexpr int   kSlabs         = 16;
constexpr int   kTilesPerSlab  = (kP1Blocks + kSlabs - 1) / kSlabs;  // 391
constexpr int   kP2Blocks      = kBuckets * kSlabs;  // 784
constexpr int   kP2Threads     = 512;                // 8 waves/block
constexpr int   kP2Waves       = kP2Threads / 64;
constexpr int   kNodeBlocks    = 200;
constexpr int   kFbBlocks      = 2048;
constexpr float kQScale        = 65536.0f;
constexpr float kQInv          = 1.0f / 65536.0f;
constexpr int   kQBias         = 524288;             // int20 bias

__device__ __forceinline__ float softplusf(float t) {
    return fmaxf(t, 0.0f) + log1pf(expf(-fabsf(t)));
}

// ---------------------------------------------------------------- pre-pass
__global__ __launch_bounds__(256) void compact_nf(
    const float4* __restrict__ nf4,   // (N,4)
    float2*       __restrict__ nfc)   // (N,) packed {vr, vi}
{
    const int i = blockIdx.x * 256 + threadIdx.x;
    if (i < kNodes) {
        const float4 v = nf4[i];
        nfc[i] = make_float2(v.x, v.y);
    }
}

// ---------------------------------------------------------------- phase 1
__global__ __launch_bounds__(256) void p1_edges(
    const float2* __restrict__ nfc,     // compact (N,) {vr,vi}
    const float*  __restrict__ logits,
    const float*  __restrict__ eparams,
    const float*  __restrict__ labels,
    const float*  __restrict__ tparams,
    const int*    __restrict__ srcs,
    const int*    __restrict__ dsts,
    unsigned*       __restrict__ pairs,    // (kP1Blocks, kEntriesPerBlk)
    unsigned short* __restrict__ offs_g,   // (kP1Blocks, kOffStride)
    float*          __restrict__ partials) // (kP1Blocks, kNumSums)
{
    __shared__ __align__(16) unsigned sorted[kEntriesPerBlk];  // 8 KB
    __shared__ int   hist[kBuckets];
    __shared__ int   offs[kBuckets + 1];
    __shared__ int   cursor[kBuckets];
    __shared__ float smem[4][kNumSums];

    const int tid = threadIdx.x;
    if (tid < kBuckets) { hist[tid] = 0; cursor[tid] = 0; }
    __syncthreads();                       // S0: init visible

    float acc[kNumSums];
#pragma unroll
    for (int k = 0; k < kNumSums; ++k) acc[k] = 0.0f;

    unsigned ent[2 * kEdgesPerThr];  // 8 packed entries (static idx, unrolled)

    const int e0 = blockIdx.x * kEdgesPerBlk;
    const int q4 = (e0 >> 2) + tid;   // index into float4/int4 views

    // ---- all index loads first
    const int4 ss = reinterpret_cast<const int4*>(srcs)[q4];
    const int4 dd = reinterpret_cast<const int4*>(dsts)[q4];

    // ---- all 8 gathers issued back-to-back (independent)
    const float2 vs0 = nfc[ss.x];
    const float2 vs1 = nfc[ss.y];
    const float2 vs2 = nfc[ss.z];
    const float2 vs3 = nfc[ss.w];
    const float2 vd0 = nfc[dd.x];
    const float2 vd1 = nfc[dd.y];
    const float2 vd2 = nfc[dd.z];
    const float2 vd3 = nfc[dd.w];

    // ---- stream loads
    const float4 lx = reinterpret_cast<const float4*>(logits)[q4];
    const float4 ly = reinterpret_cast<const float4*>(labels)[q4];
    const float4 ea = reinterpret_cast<const float4*>(eparams)[2 * q4];
    const float4 eb = reinterpret_cast<const float4*>(eparams)[2 * q4 + 1];
    const float4 ta = reinterpret_cast<const float4*>(tparams)[2 * q4];
    const float4 tb = reinterpret_cast<const float4*>(tparams)[2 * q4 + 1];

    const float xs[4]  = {lx.x, lx.y, lx.z, lx.w};
    const float ys[4]  = {ly.x, ly.y, ly.z, ly.w};
    const float epr[4] = {ea.x, ea.z, eb.x, eb.z};
    const float epx[4] = {ea.y, ea.w, eb.y, eb.w};
    const float tpr[4] = {ta.x, ta.z, tb.x, tb.z};
    const float tpx[4] = {ta.y, ta.w, tb.y, tb.w};
    const float2 vss[4] = {vs0, vs1, vs2, vs3};
    const float2 vdd[4] = {vd0, vd1, vd2, vd3};
    const int    sn[4]  = {ss.x, ss.y, ss.z, ss.w};
    const int    dn[4]  = {dd.x, dd.y, dd.z, dd.w};

    unsigned bp0 = 0, bp1 = 0;
#pragma unroll
    for (int j = 0; j < kEdgesPerThr; ++j) {
        const float x = xs[j], y = ys[j];
        const float er = epr[j], ex = epx[j];

        const float t      = __expf(-fabsf(x));
        const float inv1pt = __builtin_amdgcn_rcpf(1.0f + t);
        const float p      = (x >= 0.0f) ? inv1pt : t * inv1pt;
        const float sp_nx  = fmaxf(-x, 0.0f) + __logf(1.0f + t); // softplus(-x)
        const float bce    = sp_nx + (1.0f - y) * x;

        const float dr  = er - tpr[j];
        const float dxx = ex - tpx[j];

        const float dvr = vss[j].x - vdd[j].x;
        const float dvi = vss[j].y - vdd[j].y;
        const float mag = sqrtf(dvr * dvr + dvi * dvi);

        const float Rp    = er + kEps;
        const float curp  = mag * rsqrtf(Rp * Rp + ex * ex) * p;
        const float vdrop = mag * p;

        acc[0] += bce;
        acc[1] += dr * dr + dxx * dxx;
        acc[2] += p;
        acc[3] += p * er;
        acc[4] += p * ex;
        acc[5] += p * er * er;
        acc[6] += p * ex * ex;
        acc[7] += vdrop;
        acc[8] += vdrop * vdrop;

        int q = __float2int_rn(curp * kQScale);
        q = max(-(kQBias - 1), min(kQBias - 1, q));

        const int bd = dn[j] >> kBucketShift;
        const int bs = sn[j] >> kBucketShift;
        atomicAdd(&hist[bd], 1);
        atomicAdd(&hist[bs], 1);

        ent[2 * j]     = ((unsigned)(dn[j] & (kBucketSize - 1)) << 20) | (unsigned)( q + kQBias);
        ent[2 * j + 1] = ((unsigned)(sn[j] & (kBucketSize - 1)) << 20) | (unsigned)(-q + kQBias);
        if (j < 2) {
            bp0 |= ((unsigned)bd) << (16 * j);
            bp0 |= ((unsigned)bs) << (16 * j + 8);
        } else {
            bp1 |= ((unsigned)bd) << (16 * (j - 2));
            bp1 |= ((unsigned)bs) << (16 * (j - 2) + 8);
        }
    }

    __syncthreads();                       // S1: histogram complete

    // ---- ALL-WAVE redundant exclusive scan (same-value writes are benign;
    //      cursor was pre-initialized at S0, hist is only read here)
    {
        const int lane = tid & 63;
        int h    = (lane < kBuckets) ? hist[lane] : 0;
        int incl = h;
#pragma unroll
        for (int o = 1; o < 64; o <<= 1) {
            int n = __shfl_up(incl, o, 64);
            if (lane >= o) incl += n;
        }
        if (lane < kBuckets + 1) offs[lane] = incl - h;  // lane 49: incl=2048,h=0
    }

    // ---- scatter registers -> bucket-sorted LDS
    {
        const unsigned bkp[2] = {bp0, bp1};
#pragma unroll
        for (int k = 0; k < 2 * kEdgesPerThr; ++k) {
            const int b   = (int)((bkp[k >> 2] >> ((k & 3) * 8)) & 0xFFu);
            const int pos = offs[b] + atomicAdd(&cursor[b], 1);
            sorted[pos] = ent[k];
        }
    }
    __syncthreads();                       // S2: sorted complete

    // ---- fully-coalesced copy-out to the block's fixed slot range
    {
        const uint4 v0 = *reinterpret_cast<const uint4*>(&sorted[tid * 4]);
        reinterpret_cast<uint4*>(pairs + (size_t)blockIdx.x * kEntriesPerBlk)[tid] = v0;
        const uint4 v1 = *reinterpret_cast<const uint4*>(&sorted[1024 + tid * 4]);
        reinterpret_cast<uint4*>(pairs + (size_t)blockIdx.x * kEntriesPerBlk)[256 + tid] = v1;
    }
    if (tid < kBuckets + 1)
        offs_g[(size_t)blockIdx.x * kOffStride + tid] = (unsigned short)offs[tid];

    // ---- block reduction of the 9 scalar sums
    const int lane = tid & 63;
    const int wave = tid >> 6;
#pragma unroll
    for (int k = 0; k < kNumSums; ++k) {
        float v = acc[k];
#pragma unroll
        for (int off = 32; off > 0; off >>= 1) v += __shfl_down(v, off, 64);
        if (lane == 0) smem[wave][k] = v;
    }
    __syncthreads();                       // S3: smem visible
    if (tid < kNumSums) {
        float v = 0.0f;
#pragma unroll
        for (int w = 0; w < 4; ++w) v += smem[w][tid];
        partials[blockIdx.x * kNumSums + tid] = v;
    }
}

// ---------------------------------------------------------------- phase 2
// 512 threads (8 waves) per block; each wave walks runs i0+wave, step 8,
// prefetching the NEXT run's offsets and first entries while LDS-accumulating
// the current run (issue-early / consume-late).
__global__ __launch_bounds__(kP2Threads) void p2_buckets(
    const unsigned*       __restrict__ pairs,
    const unsigned short* __restrict__ offs_g,
    int*                  __restrict__ out_i32)  // (kP2Blocks, kBucketSize)
{
    __shared__ int accs[kBucketSize];
    const int b    = blockIdx.x / kSlabs;
    const int slab = blockIdx.x % kSlabs;

    for (int i = threadIdx.x; i < kBucketSize; i += kP2Threads) accs[i] = 0;
    __syncthreads();

    const int i0 = slab * kTilesPerSlab;
    const int i1 = min(i0 + kTilesPerSlab, kP1Blocks);
    const int lane = threadIdx.x & 63;
    const int wave = threadIdx.x >> 6;

    int i = i0 + wave;
    if (i < i1) {
        // prime: offsets + entry for run i
        int o0 = (int)offs_g[(size_t)i * kOffStride + b];
        int o1 = (int)offs_g[(size_t)i * kOffStride + b + 1];
        unsigned u    = 0;
        bool     has  = (o0 + lane) < o1;
        if (has) u = pairs[(size_t)i * kEntriesPerBlk + o0 + lane];

        for (; i < i1; ) {
            const int ni = i + kP2Waves;
            int no0 = 0, no1 = 0;
            unsigned nu = 0;
            bool nhas = false;
            if (ni < i1) {
                // issue next run's offset loads + first entry batch early
                no0 = (int)offs_g[(size_t)ni * kOffStride + b];
                no1 = (int)offs_g[(size_t)ni * kOffStride + b + 1];
                nhas = (no0 + lane) < no1;
                if (nhas) nu = pairs[(size_t)ni * kEntriesPerBlk + no0 + lane];
            }

            // accumulate current run (first batch from prefetch, rest rare)
            if (has) atomicAdd(&accs[u >> 20], (int)(u & 0xFFFFFu) - kQBias);
            const unsigned* pb = pairs + (size_t)i * kEntriesPerBlk;
            for (int j = o0 + 64 + lane; j < o1; j += 64) {
                const unsigned w = pb[j];
                atomicAdd(&accs[w >> 20], (int)(w & 0xFFFFFu) - kQBias);
            }

            i = ni; o0 = no0; o1 = no1; u = nu; has = nhas;
        }
    }
    __syncthreads();

    int* o = out_i32 + (size_t)blockIdx.x * kBucketSize;
    for (int i2 = threadIdx.x; i2 < kBucketSize; i2 += kP2Threads) o[i2] = accs[i2];
}

// ---------------------------------------------------------------- node pass
__global__ __launch_bounds__(256) void node_pass_binned(
    const int* __restrict__ out_i32,
    float*     __restrict__ node_partials)
{
    float acc = 0.0f;
    const int stride = gridDim.x * blockDim.x;
    // 4 consecutive nodes per thread via int4 (200000 % 4 == 0)
    for (int n4 = blockIdx.x * blockDim.x + threadIdx.x; n4 < kNodes / 4; n4 += stride) {
        const int n = n4 * 4;
        const int b = n >> kBucketShift;
        const int s = n & (kBucketSize - 1);
        const int* p = out_i32 + ((size_t)b * kSlabs) * kBucketSize + s;
        int4 v = make_int4(0, 0, 0, 0);
#pragma unroll
        for (int m = 0; m < kSlabs; ++m) {
            const int4 w = *reinterpret_cast<const int4*>(p + (size_t)m * kBucketSize);
            v.x += w.x; v.y += w.y; v.z += w.z; v.w += w.w;
        }
        const float f0 = (float)v.x * kQInv;
        const float f1 = (float)v.y * kQInv;
        const float f2 = (float)v.z * kQInv;
        const float f3 = (float)v.w * kQInv;
        acc += f0 * f0 + f1 * f1 + f2 * f2 + f3 * f3;
    }
    __shared__ float smem[4];
    const int lane = threadIdx.x & 63;
    const int wave = threadIdx.x >> 6;
    float v = acc;
#pragma unroll
    for (int off = 32; off > 0; off >>= 1) v += __shfl_down(v, off, 64);
    if (lane == 0) smem[wave] = v;
    __syncthreads();
    if (threadIdx.x == 0)
        node_partials[blockIdx.x] = smem[0] + smem[1] + smem[2] + smem[3];
}

// ---------------------------------------------------------------- fallback (atomic path)
__global__ __launch_bounds__(256) void edge_pass_atomic(
    const float* __restrict__ nf, const float* __restrict__ logits,
    const float* __restrict__ eparams, const float* __restrict__ labels,
    const float* __restrict__ tparams, const int* __restrict__ srcs,
    const int* __restrict__ dsts, float* __restrict__ node_cur,
    float* __restrict__ partials)
{
    float acc[kNumSums];
#pragma unroll
    for (int k = 0; k < kNumSums; ++k) acc[k] = 0.0f;
    const int stride = gridDim.x * blockDim.x;
    for (int e = blockIdx.x * blockDim.x + threadIdx.x; e < kEdges; e += stride) {
        float  x  = logits[e];
        float  y  = labels[e];
        float2 ep = *reinterpret_cast<const float2*>(eparams + 2 * e);
        float2 tp = *reinterpret_cast<const float2*>(tparams + 2 * e);
        int    s  = srcs[e];
        int    d  = dsts[e];
        float2 vs = *reinterpret_cast<const float2*>(nf + 4 * s);
        float2 vd = *reinterpret_cast<const float2*>(nf + 4 * d);
        float p   = 1.0f / (1.0f + expf(-x));
        float bce = y * softplusf(-x) + (1.0f - y) * softplusf(x);
        float dr = ep.x - tp.x, dxx = ep.y - tp.y;
        float dvr = vs.x - vd.x, dvi = vs.y - vd.y;
        float mag = sqrtf(dvr * dvr + dvi * dvi);
        float Rp  = ep.x + kEps;
        float den = sqrtf(Rp * Rp + ep.y * ep.y);
        float curp = (mag / den) * p;
        float vdrop = mag * p;
        acc[0] += bce; acc[1] += dr * dr + dxx * dxx; acc[2] += p;
        acc[3] += p * ep.x; acc[4] += p * ep.y;
        acc[5] += p * ep.x * ep.x; acc[6] += p * ep.y * ep.y;
        acc[7] += vdrop; acc[8] += vdrop * vdrop;
        atomicAdd(node_cur + d,  curp);
        atomicAdd(node_cur + s, -curp);
    }
    __shared__ float smem[4][kNumSums];
    const int lane = threadIdx.x & 63, wave = threadIdx.x >> 6;
#pragma unroll
    for (int k = 0; k < kNumSums; ++k) {
        float v = acc[k];
#pragma unroll
        for (int off = 32; off > 0; off >>= 1) v += __shfl_down(v, off, 64);
        if (lane == 0) smem[wave][k] = v;
    }
    __syncthreads();
    if (threadIdx.x < kNumSums) {
        float v = 0.0f;
#pragma unroll
        for (int w = 0; w < 4; ++w) v += smem[w][threadIdx.x];
        partials[blockIdx.x * kNumSums + threadIdx.x] = v;
    }
}

__global__ __launch_bounds__(256) void node_pass_flat(
    const float* __restrict__ node_cur, float* __restrict__ node_partials)
{
    float acc = 0.0f;
    const int stride = gridDim.x * blockDim.x;
    for (int i = blockIdx.x * blockDim.x + threadIdx.x; i < kNodes; i += stride) {
        float v = node_cur[i];
        acc += v * v;
    }
    __shared__ float smem[4];
    const int lane = threadIdx.x & 63, wave = threadIdx.x >> 6;
    float v = acc;
#pragma unroll
    for (int off = 32; off > 0; off >>= 1) v += __shfl_down(v, off, 64);
    if (lane == 0) smem[wave] = v;
    __syncthreads();
    if (threadIdx.x == 0)
        node_partials[blockIdx.x] = smem[0] + smem[1] + smem[2] + smem[3];
}

// ---------------------------------------------------------------- finalize
__global__ __launch_bounds__(256) void finalize(
    const float* __restrict__ partials, int nblocks,
    const float* __restrict__ node_partials, int nnp,
    float*       __restrict__ out)
{
    const int tid  = threadIdx.x;
    const int lane = tid & 63;
    const int wave = tid >> 6;
    __shared__ double red[4][kNumSums + 1];

    double s[kNumSums];
#pragma unroll
    for (int k = 0; k < kNumSums; ++k) s[k] = 0.0;
    for (int i = tid; i < nblocks; i += 256) {
#pragma unroll
        for (int k = 0; k < kNumSums; ++k)
            s[k] += (double)partials[i * kNumSums + k];
    }
    double ns = 0.0;
    for (int i = tid; i < nnp; i += 256) ns += (double)node_partials[i];

#pragma unroll
    for (int k = 0; k < kNumSums + 1; ++k) {
        double v = (k < kNumSums) ? s[k] : ns;
#pragma unroll
        for (int off = 32; off > 0; off >>= 1) v += __shfl_down(v, off, 64);
        if (lane == 0) red[wave][k] = v;
    }
    __syncthreads();

    if (tid == 0) {
        double sums[kNumSums + 1];
#pragma unroll
        for (int k = 0; k < kNumSums + 1; ++k)
            sums[k] = red[0][k] + red[1][k] + red[2][k] + red[3][k];

        const double E = (double)kEdges, N = (double)kNodes;
        const double s_bce = sums[0], s_par = sums[1], s_p = sums[2];
        const double s_pR = sums[3], s_pX = sums[4];
        const double s_pR2 = sums[5], s_pX2 = sums[6];
        const double s_v = sums[7], s_v2 = sums[8];
        const double nsum = sums[9];

        double topology  = s_bce / E;
        double parameter = s_par / (2.0 * E);
        double kcl       = 0.1 * (nsum / N);

        double denom = s_p + (double)kEps;
        double mR = s_pR / denom, mX = s_pX / denom;
        double varR = s_pR2 - 2.0 * mR * s_pR + mR * mR * s_p;
        double varX = s_pX2 - 2.0 * mX * s_pX + mX * mX * s_p;
        double param_consistency = 0.5 * (varR + varX);
        double voltage_consistency = (s_v2 - (s_v * s_v) / E) / (E - 1.0);
        double kvl = 0.1 * (param_consistency + voltage_consistency);

        double ecl = s_p - (N - 1.0);
        ecl = ecl * ecl;
        double radial   = 0.1 * (ecl + 0.1 * (s_p / E));
        double sparsity = 0.01 * (s_p / E);
        double total = topology + parameter + kcl + kvl + radial + sparsity;

        out[0] = (float)topology;  out[1] = (float)parameter;
        out[2] = (float)kcl;       out[3] = (float)kvl;
        out[4] = (float)radial;    out[5] = (float)sparsity;
        out[6] = (float)total;
    }
}

extern "C" void kernel_launch(void* const* d_in, const int* in_sizes, int n_in,
                              void* d_out, int out_size, void* d_ws, size_t ws_size,
                              hipStream_t stream) {
    const float* nf      = (const float*)d_in[0];
    const float* logits  = (const float*)d_in[1];
    const float* eparams = (const float*)d_in[2];
    const float* labels  = (const float*)d_in[3];
    const float* tparams = (const float*)d_in[4];
    const int*   eidx    = (const int*)d_in[5];
    float* out           = (float*)d_out;

    // layout (words): [pairs][out_i32][nfc][offs(u16)][partials][node_partials]
    const size_t n_pairs  = (size_t)kP1Blocks * kEntriesPerBlk;          // 12.8M
    const size_t n_outi32 = (size_t)kP2Blocks * kBucketSize;             // 3.21M
    const size_t n_nfc    = (size_t)kNodes * 2;                          // 400K
    const size_t n_offs_w = ((size_t)kP1Blocks * kOffStride + 1) / 2 + 64;
    const size_t n_words  = n_pairs + n_outi32 + n_nfc + n_offs_w +
                            (size_t)kP1Blocks * kNumSums + kNodeBlocks;

    if (ws_size >= n_words * sizeof(unsigned)) {
        unsigned*       pairs         = (unsigned*)d_ws;
        int*            out_i32       = (int*)(pairs + n_pairs);
        float2*         nfc           = (float2*)(out_i32 + n_outi32);
        unsigned short* offs_g        = (unsigned short*)((unsigned*)nfc + n_nfc);
        float*          partials      = (float*)((unsigned*)offs_g + n_offs_w);
        float*          node_partials = partials + (size_t)kP1Blocks * kNumSums;

        compact_nf<<<(kNodes + 255) / 256, 256, 0, stream>>>(
            (const float4*)nf, nfc);
        p1_edges<<<kP1Blocks, 256, 0, stream>>>(nfc, logits, eparams, labels,
                                                tparams, eidx, eidx + kEdges,
                                                pairs, offs_g, partials);
        p2_buckets<<<kP2Blocks, kP2Threads, 0, stream>>>(pairs, offs_g, out_i32);
        node_pass_binned<<<kNodeBlocks, 256, 0, stream>>>(out_i32, node_partials);
        finalize<<<1, 256, 0, stream>>>(partials, kP1Blocks, node_partials,
                                        kNodeBlocks, out);
    } else {
        float* node_cur      = (float*)d_ws;
        float* partials      = node_cur + kNodes;
        float* node_partials = partials + (size_t)kFbBlocks * kNumSums;

        hipMemsetAsync(node_cur, 0, kNodes * sizeof(float), stream);
        edge_pass_atomic<<<kFbBlocks, 256, 0, stream>>>(nf, logits, eparams, labels,
                                                        tparams, eidx, eidx + kEdges,
                                                        node_cur, partials);
        node_pass_flat<<<kNodeBlocks, 256, 0, stream>>>(node_cur, node_partials);
        finalize<<<1, 256, 0, stream>>>(partials, kFbBlocks, node_partials,
                                        kNodeBlocks, out);
    }
}